// Round 1
// baseline (14021.524 us; speedup 1.0000x reference)
//
#include <hip/hip_runtime.h>
#include <cstdint>
#include <cstddef>

namespace {

constexpr int B = 16, S = 768, BS = B * S, D = 512, FF = 2048, L = 6;
constexpr float EPS = 1e-5f;

__device__ __forceinline__ float wave_sum(float v) {
#pragma unroll
  for (int o = 32; o > 0; o >>= 1) v += __shfl_xor(v, o, 64);
  return v;
}

// ---------------- generic fp32 GEMM: C = [relu](A@W + bias) [+ resid] ----
// A: (M,K) lda, W: (K,N) ldw row-major, C: (M,N) ldc.
// resid: optional, row index = rmod ? m % rmod : m, leading dim ldr.
template <bool RELU>
__global__ __launch_bounds__(256) void gemm_f32(
    const float* __restrict__ A, int lda, const float* __restrict__ W, int ldw,
    const float* __restrict__ bias, const float* __restrict__ resid, int ldr,
    int rmod, float* __restrict__ C, int ldc, int M, int N, int K) {
  __shared__ float sA[16][65];  // k-major, padded (write bank-spread)
  __shared__ float sB[16][64];
  const int bn = blockIdx.x * 64;
  const int bm = blockIdx.y * 64;
  const int tid = threadIdx.x;
  const int tx = tid & 15, ty = tid >> 4;
  const int a_c = tid & 15, a_r0 = tid >> 4;
  const int b_c = tid & 63, b_r0 = tid >> 6;
  float acc[4][4] = {};
  for (int k0 = 0; k0 < K; k0 += 16) {
#pragma unroll
    for (int j = 0; j < 4; ++j) {
      int r = a_r0 + 16 * j;
      sA[a_c][r] = A[(size_t)(bm + r) * lda + (k0 + a_c)];
    }
#pragma unroll
    for (int j = 0; j < 4; ++j) {
      int r = b_r0 + 4 * j;
      sB[r][b_c] = W[(size_t)(k0 + r) * ldw + (bn + b_c)];
    }
    __syncthreads();
#pragma unroll
    for (int k = 0; k < 16; ++k) {
      float av[4], bv[4];
#pragma unroll
      for (int i = 0; i < 4; ++i) av[i] = sA[k][ty * 4 + i];
#pragma unroll
      for (int j = 0; j < 4; ++j) bv[j] = sB[k][tx * 4 + j];
#pragma unroll
      for (int i = 0; i < 4; ++i)
#pragma unroll
        for (int j = 0; j < 4; ++j) acc[i][j] = fmaf(av[i], bv[j], acc[i][j]);
    }
    __syncthreads();
  }
#pragma unroll
  for (int i = 0; i < 4; ++i) {
    int m = bm + ty * 4 + i;
#pragma unroll
    for (int j = 0; j < 4; ++j) {
      int n = bn + tx * 4 + j;
      float v = acc[i][j];
      if (bias) v += bias[n];
      if (RELU) v = fmaxf(v, 0.f);
      if (resid) {
        int rr = rmod ? (m % rmod) : m;
        v += resid[(size_t)rr * ldr + n];
      }
      C[(size_t)m * ldc + n] = v;
    }
  }
}

// ------------- fused 4-scale dilated conv + alpha mix + residual ---------
// h: (B,S,D); wt: (4,3,D,D) [scale][tap][in][out]; cb: (4,D); alpha: (B,4)
// out[b,s,o] = sum_i alpha[b,i]*(conv_i + cb[i,o]) + h[b,s,o]
__global__ __launch_bounds__(256) void conv_mix_k(
    const float* __restrict__ h, const float* __restrict__ wt,
    const float* __restrict__ cb, const float* __restrict__ alpha,
    float* __restrict__ out) {
  __shared__ float sA[16][65];
  __shared__ float sB[16][64];
  const int bn = blockIdx.x * 64;
  const int bm = blockIdx.y * 64;   // 64 | S, tile stays within one b
  const int b = bm / S;
  const int s0 = bm % S;
  const int tid = threadIdx.x;
  const int tx = tid & 15, ty = tid >> 4;
  const int a_c = tid & 15, a_r0 = tid >> 4;
  const int b_c = tid & 63, b_r0 = tid >> 6;
  const float* hb = h + (size_t)b * S * D;
  float accT[4][4] = {};
  for (int i = 0; i < 4; ++i) {   // scale, dilation 2^i
    const int dd = 1 << i;
    float acc[4][4] = {};
    for (int k = 0; k < 3; ++k) {
      const int off = (k - 1) * dd;
      const float* Wk = wt + (size_t)(i * 3 + k) * D * D;
      for (int kc = 0; kc < D; kc += 16) {
#pragma unroll
        for (int j = 0; j < 4; ++j) {
          int r = a_r0 + 16 * j;
          int s = s0 + r + off;
          sA[a_c][r] = ((unsigned)s < (unsigned)S)
                           ? hb[(size_t)s * D + kc + a_c] : 0.f;
        }
#pragma unroll
        for (int j = 0; j < 4; ++j) {
          int rr = b_r0 + 4 * j;
          sB[rr][b_c] = Wk[(size_t)(kc + rr) * D + bn + b_c];
        }
        __syncthreads();
#pragma unroll
        for (int kk = 0; kk < 16; ++kk) {
          float av[4], bv[4];
#pragma unroll
          for (int ii = 0; ii < 4; ++ii) av[ii] = sA[kk][ty * 4 + ii];
#pragma unroll
          for (int jj = 0; jj < 4; ++jj) bv[jj] = sB[kk][tx * 4 + jj];
#pragma unroll
          for (int ii = 0; ii < 4; ++ii)
#pragma unroll
            for (int jj = 0; jj < 4; ++jj)
              acc[ii][jj] = fmaf(av[ii], bv[jj], acc[ii][jj]);
        }
        __syncthreads();
      }
    }
    float al = alpha[b * 4 + i];
#pragma unroll
    for (int ii = 0; ii < 4; ++ii)
#pragma unroll
      for (int jj = 0; jj < 4; ++jj)
        accT[ii][jj] =
            fmaf(al, acc[ii][jj] + cb[i * D + bn + tx * 4 + jj], accT[ii][jj]);
  }
#pragma unroll
  for (int ii = 0; ii < 4; ++ii) {
    int m = bm + ty * 4 + ii;
#pragma unroll
    for (int jj = 0; jj < 4; ++jj) {
      int n = bn + tx * 4 + jj;
      out[(size_t)m * D + n] = accT[ii][jj] + h[(size_t)m * D + n];
    }
  }
}

// ---------------- conv weight transpose: (4,O,I,3) -> (4,3,I,O) ----------
__global__ __launch_bounds__(256) void convw_t_k(const float* __restrict__ cw,
                                                 float* __restrict__ wt) {
  int t = blockIdx.x * 256 + threadIdx.x;
  if (t >= 4 * 512 * 512) return;
  int o = t & 511;
  int kin = (t >> 9) & 511;
  int i = t >> 18;
  const float* src = cw + (((size_t)i * 512 + o) * 512 + kin) * 3;
#pragma unroll
  for (int k = 0; k < 3; ++k)
    wt[(((size_t)(i * 3 + k)) * 512 + kin) * 512 + o] = src[k];
}

// ---------------- row LayerNorm over D=512, one wave per row -------------
__global__ __launch_bounds__(256) void layernorm_k(
    const float* __restrict__ x, const float* __restrict__ g,
    const float* __restrict__ b, float* __restrict__ out) {
  int row = blockIdx.x * 4 + (threadIdx.x >> 6);
  int lane = threadIdx.x & 63;
  const float* xr = x + (size_t)row * D;
  float v[8];
  float s = 0.f;
#pragma unroll
  for (int j = 0; j < 8; ++j) { v[j] = xr[lane + 64 * j]; s += v[j]; }
  s = wave_sum(s);
  float mean = s * (1.f / D);
  float q = 0.f;
#pragma unroll
  for (int j = 0; j < 8; ++j) { float d = v[j] - mean; q += d * d; }
  q = wave_sum(q);
  float rstd = rsqrtf(q * (1.f / D) + EPS);
  float* orow = out + (size_t)row * D;
#pragma unroll
  for (int j = 0; j < 8; ++j) {
    int c = lane + 64 * j;
    orow[c] = (v[j] - mean) * rstd * g[c] + b[c];
  }
}

// ---------------- partial column means over S (deterministic) ------------
// part[b, c, d] = sum_{s in chunk c (64)} x[b,s,d]
__global__ __launch_bounds__(256) void colmean_part_k(
    const float* __restrict__ x, float* __restrict__ part) {
  int b = blockIdx.x, c = blockIdx.y;
  int t = threadIdx.x;
  int s0 = c * 64;
  for (int d = t; d < D; d += 256) {
    float s = 0.f;
    for (int si = 0; si < 64; ++si)
      s += x[((size_t)b * S + s0 + si) * D + d];
    part[((size_t)b * 12 + c) * D + d] = s;
  }
}

// ---------------- alpha = softmax(mean_s(h) @ wmw + wmb) -----------------
__global__ __launch_bounds__(64) void alpha_k(const float* __restrict__ part,
                                              const float* __restrict__ wmw,
                                              const float* __restrict__ wmb,
                                              float* __restrict__ alpha) {
  int b = blockIdx.x, t = threadIdx.x;
  float p0 = 0, p1 = 0, p2 = 0, p3 = 0;
  for (int d = t; d < D; d += 64) {
    float xm = 0;
#pragma unroll
    for (int c = 0; c < 12; ++c) xm += part[((size_t)b * 12 + c) * D + d];
    xm *= (1.f / S);
    p0 += xm * wmw[d * 4 + 0];
    p1 += xm * wmw[d * 4 + 1];
    p2 += xm * wmw[d * 4 + 2];
    p3 += xm * wmw[d * 4 + 3];
  }
  p0 = wave_sum(p0); p1 = wave_sum(p1); p2 = wave_sum(p2); p3 = wave_sum(p3);
  if (t == 0) {
    float l0 = p0 + wmb[0], l1 = p1 + wmb[1], l2 = p2 + wmb[2], l3 = p3 + wmb[3];
    float mx = fmaxf(fmaxf(l0, l1), fmaxf(l2, l3));
    float e0 = expf(l0 - mx), e1 = expf(l1 - mx), e2 = expf(l2 - mx),
          e3 = expf(l3 - mx);
    float inv = 1.f / (e0 + e1 + e2 + e3);
    alpha[b * 4 + 0] = e0 * inv;
    alpha[b * 4 + 1] = e1 * inv;
    alpha[b * 4 + 2] = e2 * inv;
    alpha[b * 4 + 3] = e3 * inv;
  }
}

// ---------------- embedding gather-mean ----------------------------------
__global__ __launch_bounds__(256) void embed_k(const int* __restrict__ xe,
                                               const float* __restrict__ emb,
                                               float* __restrict__ out) {
  int r = blockIdx.x, t = threadIdx.x;
  int idx[8];
#pragma unroll
  for (int j = 0; j < 8; ++j) idx[j] = xe[r * 8 + j];
  for (int d = t; d < D; d += 256) {
    float s = 0.f;
#pragma unroll
    for (int j = 0; j < 8; ++j) s += emb[(size_t)idx[j] * D + d];
    out[(size_t)r * D + d] = s * 0.125f;
  }
}

// ---------------- L2-normalize rows of (BS,64), one wave per row ---------
__global__ __launch_bounds__(256) void norml2_k(const float* __restrict__ x,
                                                float* __restrict__ out) {
  int r = blockIdx.x * 4 + (threadIdx.x >> 6);
  int lane = threadIdx.x & 63;
  float v = x[(size_t)r * 64 + lane];
  float s = wave_sum(v * v);
  float n = fmaxf(sqrtf(s), 1e-12f);
  out[(size_t)r * 64 + lane] = v / n;
}

// ---------------- classifier head: relu(hg@pw1+pb1)@pw2+pb2 --------------
__global__ __launch_bounds__(256) void head_k(
    const float* __restrict__ part, const float* __restrict__ pw1,
    const float* __restrict__ pb1, const float* __restrict__ pw2,
    const float* __restrict__ pb2, float* __restrict__ out) {
  __shared__ float hg[D];
  __shared__ float red[256];
  int b = blockIdx.x, t = threadIdx.x;
  for (int d = t; d < D; d += 256) {
    float s = 0.f;
#pragma unroll
    for (int c = 0; c < 12; ++c) s += part[((size_t)b * 12 + c) * D + d];
    hg[d] = s * (1.f / S);
  }
  __syncthreads();
  float s = pb1[t];
  for (int d = 0; d < D; ++d) s = fmaf(hg[d], pw1[(size_t)d * 256 + t], s);
  s = fmaxf(s, 0.f);
  red[t] = s * pw2[t];
  __syncthreads();
  for (int o = 128; o > 0; o >>= 1) {
    if (t < o) red[t] += red[t + o];
    __syncthreads();
  }
  if (t == 0) out[b] = red[0] + pb2[0];
}

}  // namespace

extern "C" void kernel_launch(void* const* d_in, const int* in_sizes, int n_in,
                              void* d_out, int out_size, void* d_ws,
                              size_t ws_size, hipStream_t stream) {
  const float* x_cog = (const float*)d_in[0];
  const float* cw1 = (const float*)d_in[1];
  const float* cb1 = (const float*)d_in[2];
  const float* cw2 = (const float*)d_in[3];
  const float* cb2 = (const float*)d_in[4];
  const float* env_emb = (const float*)d_in[5];
  const float* ew1 = (const float*)d_in[6];
  const float* eb1 = (const float*)d_in[7];
  const float* ew2 = (const float*)d_in[8];
  const float* eb2 = (const float*)d_in[9];
  const float* fw1 = (const float*)d_in[10];
  const float* fb1 = (const float*)d_in[11];
  const float* fw2 = (const float*)d_in[12];
  const float* fb2 = (const float*)d_in[13];
  const float* pos_enc = (const float*)d_in[14];
  const float* conv_w = (const float*)d_in[15];
  const float* conv_b = (const float*)d_in[16];
  const float* wm_w = (const float*)d_in[17];
  const float* wm_b = (const float*)d_in[18];
  // d_in[19..21] = ssm_w, ssm_b, A_log: provably no-ops (LN shift-invariance)
  const float* ffw1 = (const float*)d_in[22];
  const float* ffb1 = (const float*)d_in[23];
  const float* ffw2 = (const float*)d_in[24];
  const float* ffb2 = (const float*)d_in[25];
  const float* g1 = (const float*)d_in[26];
  const float* be1 = (const float*)d_in[27];
  const float* g2 = (const float*)d_in[28];
  const float* be2 = (const float*)d_in[29];
  const float* pw1 = (const float*)d_in[30];
  const float* pb1 = (const float*)d_in[31];
  const float* pw2 = (const float*)d_in[32];
  const float* pb2 = (const float*)d_in[33];
  const int* x_env = (const int*)d_in[34];
  float* out = (float*)d_out;

  float* ws = (float*)d_ws;
  float* BIGB = ws;                            // BS*2048 (concat hf / FF hidden)
  float* Hbuf = BIGB + (size_t)BS * FF;        // BS*512 running h
  float* TA = Hbuf + (size_t)BS * D;           // BS*512 temp
  float* TB = TA + (size_t)BS * D;             // BS*512 temp
  float* WT = TB + (size_t)BS * D;             // 4*3*512*512 conv wt transposed
  float* PART = WT + (size_t)4 * 3 * D * D;    // 16*12*512 colmean partials
  float* ALPHAB = PART + (size_t)B * 12 * D;   // 64

  dim3 blk(256);
  dim3 gD(D / 64, BS / 64);

  // ---- frontend ----
  norml2_k<<<BS / 4, blk, 0, stream>>>(x_cog, TA);
  gemm_f32<true><<<gD, blk, 0, stream>>>(TA, 64, cw1, D, cb1, nullptr, 0, 0,
                                         TB, D, BS, D, 64);
  gemm_f32<false><<<gD, blk, 0, stream>>>(TB, D, cw2, D, cb2, nullptr, 0, 0,
                                          BIGB, 2 * D, BS, D, D);
  embed_k<<<BS, blk, 0, stream>>>(x_env, env_emb, TA);
  gemm_f32<true><<<gD, blk, 0, stream>>>(TA, D, ew1, D, eb1, nullptr, 0, 0,
                                         TB, D, BS, D, D);
  gemm_f32<false><<<gD, blk, 0, stream>>>(TB, D, ew2, D, eb2, nullptr, 0, 0,
                                          BIGB + D, 2 * D, BS, D, D);
  gemm_f32<true><<<gD, blk, 0, stream>>>(BIGB, 2 * D, fw1, D, fb1, nullptr, 0,
                                         0, TA, D, BS, D, 2 * D);
  gemm_f32<false><<<gD, blk, 0, stream>>>(TA, D, fw2, D, fb2, pos_enc, D, S,
                                          Hbuf, D, BS, D, D);

  // ---- layers ----
  for (int l = 0; l < L; ++l) {
    convw_t_k<<<4 * 512 * 512 / 256, blk, 0, stream>>>(
        conv_w + (size_t)l * 4 * D * D * 3, WT);
    colmean_part_k<<<dim3(B, 12), blk, 0, stream>>>(Hbuf, PART);
    alpha_k<<<B, dim3(64), 0, stream>>>(PART, wm_w + (size_t)l * D * 4,
                                        wm_b + l * 4, ALPHAB);
    conv_mix_k<<<gD, blk, 0, stream>>>(Hbuf, WT, conv_b + (size_t)l * 4 * D,
                                       ALPHAB, TA);
    layernorm_k<<<BS / 4, blk, 0, stream>>>(TA, g1 + l * D, be1 + l * D, TB);
    // SSM output y is scalar-per-row -> cancels in LN2 (shift invariance).
    layernorm_k<<<BS / 4, blk, 0, stream>>>(TB, g2 + l * D, be2 + l * D, TA);
    gemm_f32<true><<<dim3(FF / 64, BS / 64), blk, 0, stream>>>(
        TA, D, ffw1 + (size_t)l * D * FF, FF, ffb1 + (size_t)l * FF, nullptr,
        0, 0, BIGB, FF, BS, FF, D);
    gemm_f32<false><<<gD, blk, 0, stream>>>(
        BIGB, FF, ffw2 + (size_t)l * FF * D, D, ffb2 + (size_t)l * D, TA, D, 0,
        Hbuf, D, BS, D, FF);
  }

  // ---- head ----
  colmean_part_k<<<dim3(B, 12), blk, 0, stream>>>(Hbuf, PART);
  head_k<<<B, blk, 0, stream>>>(PART, pw1, pb1, pw2, pb2, out);
}

// Round 2
// 4179.194 us; speedup vs baseline: 3.3551x; 3.3551x over previous
//
#include <hip/hip_runtime.h>
#include <cstdint>
#include <cstddef>

namespace {

constexpr int B = 16, S = 768, BS = B * S, D = 512, FF = 2048, L = 6;
constexpr float EPS = 1e-5f;

typedef float f32x4 __attribute__((ext_vector_type(4)));
typedef short bf16x8 __attribute__((ext_vector_type(8)));

__device__ __forceinline__ float wave_sum(float v) {
#pragma unroll
  for (int o = 32; o > 0; o >>= 1) v += __shfl_xor(v, o, 64);
  return v;
}

// ---- bf16 split helpers (RTNE) ------------------------------------------
__device__ __forceinline__ short bfhi(float x) {
  uint32_t u = __float_as_uint(x);
  u += 0x7fffu + ((u >> 16) & 1u);
  return (short)(u >> 16);
}
__device__ __forceinline__ float bf2f(short h) {
  return __uint_as_float(((uint32_t)(unsigned short)h) << 16);
}
__device__ __forceinline__ void split_bf(float x, short& hi, short& lo) {
  hi = bfhi(x);
  lo = bfhi(x - bf2f(hi));
}

// ---- async global->LDS, 16B per lane ------------------------------------
__device__ __forceinline__ void gload16(const void* g, void* l) {
  __builtin_amdgcn_global_load_lds(
      (const __attribute__((address_space(1))) void*)g,
      (__attribute__((address_space(3))) void*)l, 16, 0, 0);
}

// =========================================================================
// Split-bf16 GEMM.  A: (M, 2K) packed [hi(K)|lo(K)] row-major.
// Wt: (N, 2K) packed [hi(K)|lo(K)] row-major (i.e. B^T, N-major).
// 3 segments: a_hi*w_hi + a_lo*w_hi + a_hi*w_lo, fp32 accum.
// OMODE 0: C=f32 (+optional resid); OMODE 1: split-pack out to ph/pl.
// Tile 128x128, BK=32, 4 waves (2x2), each wave 64x64 via 4x4 frags.
// =========================================================================
template <bool RELU, int OMODE>
__global__ __launch_bounds__(256) void gemm_sp3(
    const short* __restrict__ A, const short* __restrict__ Wt, int K,
    const float* __restrict__ bias, const float* __restrict__ resid, int ldr,
    int rmod, float* __restrict__ C, int ldc, short* __restrict__ ph,
    short* __restrict__ pl, int ldp) {
  __shared__ alignas(16) short sA[4096];   // [128 rows][32 k]
  __shared__ alignas(16) short sB[4096];
  const int tid = threadIdx.x;
  const int bn = blockIdx.x * 128, bm = blockIdx.y * 128;
  const int wave = tid >> 6, lane = tid & 63;
  const int wr = (wave >> 1) * 64, wc = (wave & 1) * 64;
  const int lr = lane & 15, kg = (lane >> 4) * 8;
  const int lda = 2 * K;
  const int ar0 = tid >> 2, ac0 = (tid & 3) * 8;  // 4 chunks of 8 elems/row
  const short* Ab = A + (size_t)bm * lda;
  const short* Wb = Wt + (size_t)bn * lda;
  f32x4 acc[4][4] = {};
  for (int seg = 0; seg < 3; ++seg) {
    const int aoff = (seg == 1) ? K : 0;
    const int woff = (seg == 2) ? K : 0;
    for (int k0 = 0; k0 < K; k0 += 32) {
#pragma unroll
      for (int i = 0; i < 2; ++i) {
        const int row = i * 64 + ar0;
        gload16(Ab + (size_t)row * lda + aoff + k0 + ac0,
                &sA[(i * 256 + tid) * 8]);
        gload16(Wb + (size_t)row * lda + woff + k0 + ac0,
                &sB[(i * 256 + tid) * 8]);
      }
      __syncthreads();
      bf16x8 af[4], bfr[4];
#pragma unroll
      for (int m = 0; m < 4; ++m)
        af[m] = *(const bf16x8*)&sA[(wr + m * 16 + lr) * 32 + kg];
#pragma unroll
      for (int n = 0; n < 4; ++n)
        bfr[n] = *(const bf16x8*)&sB[(wc + n * 16 + lr) * 32 + kg];
#pragma unroll
      for (int m = 0; m < 4; ++m)
#pragma unroll
        for (int n = 0; n < 4; ++n)
          acc[m][n] = __builtin_amdgcn_mfma_f32_16x16x32_bf16(
              af[m], bfr[n], acc[m][n], 0, 0, 0);
      __syncthreads();
    }
  }
  // epilogue: C/D layout row=(lane>>4)*4+r, col=lane&15   [m89-verified]
  const int r4 = (lane >> 4) * 4;
#pragma unroll
  for (int m = 0; m < 4; ++m) {
#pragma unroll
    for (int r = 0; r < 4; ++r) {
      const int mm = bm + wr + m * 16 + r4 + r;
#pragma unroll
      for (int n = 0; n < 4; ++n) {
        const int col = bn + wc + n * 16 + lr;
        float v = acc[m][n][r] + bias[col];
        if (RELU) v = fmaxf(v, 0.f);
        if (OMODE == 0) {
          if (resid) {
            const int rr = rmod ? (mm % rmod) : mm;
            v += resid[(size_t)rr * ldr + col];
          }
          C[(size_t)mm * ldc + col] = v;
        } else {
          short hi, lo;
          split_bf(v, hi, lo);
          ph[(size_t)mm * ldp + col] = hi;
          pl[(size_t)mm * ldp + col] = lo;
        }
      }
    }
  }
}

// =========================================================================
// Conv implicit GEMM: per scale z (dilation 1<<z), 3 taps, split-3 over K=512.
// hp: (B, 768, 1024) packed h; wt: (12, 512, 1024) packed (N-major) weights.
// OOB rows (s outside [0,768)) read from a zero page (per-lane global addr).
// Y[z]: (12288, 512) f32, no bias (alpha-mix handles cb).
// =========================================================================
__global__ __launch_bounds__(256) void conv_gemm_k(
    const short* __restrict__ hp, const short* __restrict__ wt,
    const short* __restrict__ zpad, float* __restrict__ Y) {
  __shared__ alignas(16) short sA[4096];
  __shared__ alignas(16) short sB[4096];
  const int z = blockIdx.z, dd = 1 << z;
  const int tid = threadIdx.x;
  const int bn = blockIdx.x * 128, bm = blockIdx.y * 128;
  const int b = bm / S, s0 = bm % S;   // 128 | 768 -> tile within one batch
  const int wave = tid >> 6, lane = tid & 63;
  const int wr = (wave >> 1) * 64, wc = (wave & 1) * 64;
  const int lr = lane & 15, kg = (lane >> 4) * 8;
  const int ar0 = tid >> 2, ac0 = (tid & 3) * 8;
  const short* hb = hp + (size_t)b * S * 1024;
  f32x4 acc[4][4] = {};
  for (int t = 0; t < 3; ++t) {
    const int off = (t - 1) * dd;
    const short* Wb = wt + ((size_t)(z * 3 + t) * 512 + bn) * 1024;
    for (int seg = 0; seg < 3; ++seg) {
      const int aoff = (seg == 1) ? 512 : 0;
      const int woff = (seg == 2) ? 512 : 0;
      for (int k0 = 0; k0 < 512; k0 += 32) {
#pragma unroll
        for (int i = 0; i < 2; ++i) {
          const int row = i * 64 + ar0;
          const int srow = s0 + row + off;
          const short* ga = ((unsigned)srow < (unsigned)S)
                                ? hb + (size_t)srow * 1024 + aoff + k0 + ac0
                                : zpad + ac0;
          gload16(ga, &sA[(i * 256 + tid) * 8]);
          gload16(Wb + (size_t)row * 1024 + woff + k0 + ac0,
                  &sB[(i * 256 + tid) * 8]);
        }
        __syncthreads();
        bf16x8 af[4], bfr[4];
#pragma unroll
        for (int m = 0; m < 4; ++m)
          af[m] = *(const bf16x8*)&sA[(wr + m * 16 + lr) * 32 + kg];
#pragma unroll
        for (int n = 0; n < 4; ++n)
          bfr[n] = *(const bf16x8*)&sB[(wc + n * 16 + lr) * 32 + kg];
#pragma unroll
        for (int m = 0; m < 4; ++m)
#pragma unroll
          for (int n = 0; n < 4; ++n)
            acc[m][n] = __builtin_amdgcn_mfma_f32_16x16x32_bf16(
                af[m], bfr[n], acc[m][n], 0, 0, 0);
        __syncthreads();
      }
    }
  }
  float* Yb = Y + (size_t)z * ((size_t)BS * D);
  const int r4 = (lane >> 4) * 4;
#pragma unroll
  for (int m = 0; m < 4; ++m)
#pragma unroll
    for (int r = 0; r < 4; ++r) {
      const int mm = bm + wr + m * 16 + r4 + r;
#pragma unroll
      for (int n = 0; n < 4; ++n)
        Yb[(size_t)mm * D + bn + wc + n * 16 + lr] = acc[m][n][r];
    }
}

// ---- out = h + sum_z alpha[b,z]*(Y[z] + cb[z,:]) -------------------------
__global__ __launch_bounds__(256) void mix_k(
    const float* __restrict__ Y, const float* __restrict__ h,
    const float* __restrict__ cb, const float* __restrict__ alpha,
    float* __restrict__ out) {
  const size_t e = ((size_t)blockIdx.x * 256 + threadIdx.x) * 4;
  const int n = (int)(e & 511);
  const int m = (int)(e >> 9);
  const int b = m / S;
  f32x4 v = *(const f32x4*)(h + e);
#pragma unroll
  for (int z = 0; z < 4; ++z) {
    const float al = alpha[b * 4 + z];
    const f32x4 y = *(const f32x4*)(Y + (size_t)z * ((size_t)BS * D) + e);
    const f32x4 c = *(const f32x4*)(cb + z * D + n);
#pragma unroll
    for (int j = 0; j < 4; ++j) v[j] += al * (y[j] + c[j]);
  }
  *(f32x4*)(out + e) = v;
}

// ---- generic A-pack: (12288,512) f32 -> (12288,1024) [hi|lo] -------------
__global__ __launch_bounds__(256) void pack_a_k(const float* __restrict__ x,
                                                short* __restrict__ out) {
  const int r = blockIdx.x;
  const float* src = x + (size_t)r * D;
  short* o = out + (size_t)r * 1024;
  for (int c = threadIdx.x; c < D; c += 256) {
    short hi, lo;
    split_bf(src[c], hi, lo);
    o[c] = hi;
    o[D + c] = lo;
  }
}

// ---- W-pack: (K,N) f32 -> (N,2K) [hi|lo] (B^T layout) --------------------
__global__ __launch_bounds__(256) void pack_w_k(const float* __restrict__ W,
                                                short* __restrict__ out,
                                                int K, int N, int ln2N) {
  const int idx = blockIdx.x * 256 + threadIdx.x;
  const int n = idx & (N - 1), k = idx >> ln2N;
  if (k >= K) return;
  short hi, lo;
  split_bf(W[(size_t)k * N + n], hi, lo);
  out[(size_t)n * 2 * K + k] = hi;
  out[(size_t)n * 2 * K + K + k] = lo;
}

// ---- conv W-pack: (4,O,I,3) -> (12=[z*3+t], O, 1024=[hi(I)|lo(I)]) -------
__global__ __launch_bounds__(256) void pack_convw_k(
    const float* __restrict__ cw, short* __restrict__ out) {
  const int idx = blockIdx.x * 256 + threadIdx.x;  // 12*512*512
  const int c = idx & 511, o = (idx >> 9) & 511, seg = idx >> 18;
  const int i = seg / 3, t = seg % 3;
  short hi, lo;
  split_bf(cw[(((size_t)i * D + o) * D + c) * 3 + t], hi, lo);
  short* dst = out + ((size_t)seg * D + o) * 1024;
  dst[c] = hi;
  dst[D + c] = lo;
}

// ---- zero page for conv OOB rows ----------------------------------------
__global__ __launch_bounds__(256) void zero_k(float* __restrict__ p) {
  p[threadIdx.x] = 0.f;
  p[threadIdx.x + 256] = 0.f;
}

// ---- LayerNorm over D=512; optional in-place f32 + optional packed out ---
__global__ __launch_bounds__(256) void layernorm_k(
    const float* __restrict__ x, const float* __restrict__ g,
    const float* __restrict__ b, float* __restrict__ fout,
    short* __restrict__ pout) {
  const int row = blockIdx.x * 4 + (threadIdx.x >> 6);
  const int lane = threadIdx.x & 63;
  const float* xr = x + (size_t)row * D;
  float v[8];
  float s = 0.f;
#pragma unroll
  for (int j = 0; j < 8; ++j) { v[j] = xr[lane + 64 * j]; s += v[j]; }
  s = wave_sum(s);
  const float mean = s * (1.f / D);
  float q = 0.f;
#pragma unroll
  for (int j = 0; j < 8; ++j) { const float d = v[j] - mean; q += d * d; }
  q = wave_sum(q);
  const float rstd = rsqrtf(q * (1.f / D) + EPS);
  float* frow = fout + (size_t)row * D;
  short* prow = pout ? pout + (size_t)row * 1024 : nullptr;
#pragma unroll
  for (int j = 0; j < 8; ++j) {
    const int c = lane + 64 * j;
    const float y = (v[j] - mean) * rstd * g[c] + b[c];
    frow[c] = y;
    if (prow) {
      short hi, lo;
      split_bf(y, hi, lo);
      prow[c] = hi;
      prow[D + c] = lo;
    }
  }
}

// ---- partial column sums over S (8 chunks x 96 rows), deterministic ------
__global__ __launch_bounds__(256) void colmean_part_k(
    const float* __restrict__ x, float* __restrict__ part) {
  const int b = blockIdx.x, c = blockIdx.y;
  const int s0 = c * 96;
  for (int d = threadIdx.x; d < D; d += 256) {
    float s = 0.f;
    for (int si = 0; si < 96; ++si)
      s += x[((size_t)b * S + s0 + si) * D + d];
    part[((size_t)b * 8 + c) * D + d] = s;
  }
}

// ---- alpha = softmax(mean_s(h) @ wmw + wmb) ------------------------------
__global__ __launch_bounds__(64) void alpha_k(const float* __restrict__ part,
                                              const float* __restrict__ wmw,
                                              const float* __restrict__ wmb,
                                              float* __restrict__ alpha) {
  const int b = blockIdx.x, t = threadIdx.x;
  float p0 = 0, p1 = 0, p2 = 0, p3 = 0;
  for (int d = t; d < D; d += 64) {
    float xm = 0;
#pragma unroll
    for (int c = 0; c < 8; ++c) xm += part[((size_t)b * 8 + c) * D + d];
    xm *= (1.f / S);
    p0 += xm * wmw[d * 4 + 0];
    p1 += xm * wmw[d * 4 + 1];
    p2 += xm * wmw[d * 4 + 2];
    p3 += xm * wmw[d * 4 + 3];
  }
  p0 = wave_sum(p0); p1 = wave_sum(p1);
  p2 = wave_sum(p2); p3 = wave_sum(p3);
  if (t == 0) {
    const float l0 = p0 + wmb[0], l1 = p1 + wmb[1];
    const float l2 = p2 + wmb[2], l3 = p3 + wmb[3];
    const float mx = fmaxf(fmaxf(l0, l1), fmaxf(l2, l3));
    const float e0 = expf(l0 - mx), e1 = expf(l1 - mx);
    const float e2 = expf(l2 - mx), e3 = expf(l3 - mx);
    const float inv = 1.f / (e0 + e1 + e2 + e3);
    alpha[b * 4 + 0] = e0 * inv;
    alpha[b * 4 + 1] = e1 * inv;
    alpha[b * 4 + 2] = e2 * inv;
    alpha[b * 4 + 3] = e3 * inv;
  }
}

// ---- embedding gather-mean, packed out -----------------------------------
__global__ __launch_bounds__(256) void embed_k(const int* __restrict__ xe,
                                               const float* __restrict__ emb,
                                               short* __restrict__ out) {
  const int r = blockIdx.x;
  int idx[8];
#pragma unroll
  for (int j = 0; j < 8; ++j) idx[j] = xe[r * 8 + j];
  short* o = out + (size_t)r * 1024;
  for (int d = threadIdx.x; d < D; d += 256) {
    float s = 0.f;
#pragma unroll
    for (int j = 0; j < 8; ++j) s += emb[(size_t)idx[j] * D + d];
    short hi, lo;
    split_bf(s * 0.125f, hi, lo);
    o[d] = hi;
    o[D + d] = lo;
  }
}

// ---- L2-normalize rows of (BS,64), packed out (K=64 -> lda 128) ----------
__global__ __launch_bounds__(256) void norml2_k(const float* __restrict__ x,
                                                short* __restrict__ out) {
  const int r = blockIdx.x * 4 + (threadIdx.x >> 6);
  const int lane = threadIdx.x & 63;
  const float v = x[(size_t)r * 64 + lane];
  const float s = wave_sum(v * v);
  const float nrm = fmaxf(sqrtf(s), 1e-12f);
  short hi, lo;
  split_bf(v / nrm, hi, lo);
  out[(size_t)r * 128 + lane] = hi;
  out[(size_t)r * 128 + 64 + lane] = lo;
}

// ---- classifier head -----------------------------------------------------
__global__ __launch_bounds__(256) void head_k(
    const float* __restrict__ part, const float* __restrict__ pw1,
    const float* __restrict__ pb1, const float* __restrict__ pw2,
    const float* __restrict__ pb2, float* __restrict__ out) {
  __shared__ float hg[D];
  __shared__ float red[256];
  const int b = blockIdx.x, t = threadIdx.x;
  for (int d = t; d < D; d += 256) {
    float s = 0.f;
#pragma unroll
    for (int c = 0; c < 8; ++c) s += part[((size_t)b * 8 + c) * D + d];
    hg[d] = s * (1.f / S);
  }
  __syncthreads();
  float s = pb1[t];
  for (int d = 0; d < D; ++d) s = fmaf(hg[d], pw1[(size_t)d * 256 + t], s);
  s = fmaxf(s, 0.f);
  red[t] = s * pw2[t];
  __syncthreads();
  for (int o = 128; o > 0; o >>= 1) {
    if (t < o) red[t] += red[t + o];
    __syncthreads();
  }
  if (t == 0) out[b] = red[0] + pb2[0];
}

}  // namespace

extern "C" void kernel_launch(void* const* d_in, const int* in_sizes, int n_in,
                              void* d_out, int out_size, void* d_ws,
                              size_t ws_size, hipStream_t stream) {
  const float* x_cog = (const float*)d_in[0];
  const float* cw1 = (const float*)d_in[1];
  const float* cb1 = (const float*)d_in[2];
  const float* cw2 = (const float*)d_in[3];
  const float* cb2 = (const float*)d_in[4];
  const float* env_emb = (const float*)d_in[5];
  const float* ew1 = (const float*)d_in[6];
  const float* eb1 = (const float*)d_in[7];
  const float* ew2 = (const float*)d_in[8];
  const float* eb2 = (const float*)d_in[9];
  const float* fw1 = (const float*)d_in[10];
  const float* fb1 = (const float*)d_in[11];
  const float* fw2 = (const float*)d_in[12];
  const float* fb2 = (const float*)d_in[13];
  const float* pos_enc = (const float*)d_in[14];
  const float* conv_w = (const float*)d_in[15];
  const float* conv_b = (const float*)d_in[16];
  const float* wm_w = (const float*)d_in[17];
  const float* wm_b = (const float*)d_in[18];
  // d_in[19..21] = ssm_w/ssm_b/A_log: no-ops (y is scalar-per-row; LayerNorm
  // shift invariance cancels it exactly).
  const float* ffw1 = (const float*)d_in[22];
  const float* ffb1 = (const float*)d_in[23];
  const float* ffw2 = (const float*)d_in[24];
  const float* ffb2 = (const float*)d_in[25];
  const float* g1 = (const float*)d_in[26];
  const float* be1 = (const float*)d_in[27];
  const float* g2 = (const float*)d_in[28];
  const float* be2 = (const float*)d_in[29];
  const float* pw1 = (const float*)d_in[30];
  const float* pb1 = (const float*)d_in[31];
  const float* pw2 = (const float*)d_in[32];
  const float* pb2 = (const float*)d_in[33];
  const int* x_env = (const int*)d_in[34];
  float* out = (float*)d_out;

  // ---- workspace arena (total 189.0 MB; round-1 proved >=189.1 MB) -------
  float* ws = (float*)d_ws;
  float* Hbuf = ws;                       // 12288x512 f32
  float* TBuf = ws + 6291456;             // 12288x512 f32
  float* PARTb = ws + 2 * 6291456;        // 16x8x512 f32
  float* ALPHAB = PARTb + 65536;          // 64 f32
  float* ZPADF = ALPHAB + 64;             // 512 f32 zero page
  short* WP = (short*)(ZPADF + 512);      // 6,291,456 shorts (W packs)
  short* R1 = WP + 6291456;               // big aliased region, 125.83 MB
  // conv phase:
  short* HPACK = R1;                      // 12288x1024
  float* Ybuf = (float*)(R1 + 12582912);  // 4x12288x512 f32
  // ff phase (aliases conv phase):
  short* APFF = R1;                       // 12288x4096
  short* APD = R1 + 50331648;             // 12288x1024
  // frontend phase (aliases both):
  short* CONC = R1;                       // 12288x2048
  short* PK1 = R1 + 25165824;             // 12288x1024
  short* PK2 = R1 + 37748736;             // 12288x1024

  const dim3 blk(256);
  const dim3 gN4(4, BS / 128);    // N=512 tiles
  const dim3 gN16(16, BS / 128);  // N=2048 tiles

  zero_k<<<1, blk, 0, stream>>>(ZPADF);

  // ---- frontend -----------------------------------------------------------
  norml2_k<<<BS / 4, blk, 0, stream>>>(x_cog, PK1);
  pack_w_k<<<64 * 512 / 256, blk, 0, stream>>>(cw1, WP, 64, 512, 9);
  gemm_sp3<true, 1><<<gN4, blk, 0, stream>>>(PK1, WP, 64, cb1, nullptr, 0, 0,
                                             nullptr, 0, PK2, PK2 + 512, 1024);
  pack_w_k<<<512 * 512 / 256, blk, 0, stream>>>(cw2, WP, 512, 512, 9);
  gemm_sp3<false, 1><<<gN4, blk, 0, stream>>>(PK2, WP, 512, cb2, nullptr, 0, 0,
                                              nullptr, 0, CONC, CONC + 1024,
                                              2048);
  embed_k<<<BS, blk, 0, stream>>>(x_env, env_emb, PK1);
  pack_w_k<<<512 * 512 / 256, blk, 0, stream>>>(ew1, WP, 512, 512, 9);
  gemm_sp3<true, 1><<<gN4, blk, 0, stream>>>(PK1, WP, 512, eb1, nullptr, 0, 0,
                                             nullptr, 0, PK2, PK2 + 512, 1024);
  pack_w_k<<<512 * 512 / 256, blk, 0, stream>>>(ew2, WP, 512, 512, 9);
  gemm_sp3<false, 1><<<gN4, blk, 0, stream>>>(PK2, WP, 512, eb2, nullptr, 0, 0,
                                              nullptr, 0, CONC + 512,
                                              CONC + 1536, 2048);
  pack_w_k<<<1024 * 512 / 256, blk, 0, stream>>>(fw1, WP, 1024, 512, 9);
  gemm_sp3<true, 1><<<gN4, blk, 0, stream>>>(CONC, WP, 1024, fb1, nullptr, 0,
                                             0, nullptr, 0, PK1, PK1 + 512,
                                             1024);
  pack_w_k<<<512 * 512 / 256, blk, 0, stream>>>(fw2, WP, 512, 512, 9);
  gemm_sp3<false, 0><<<gN4, blk, 0, stream>>>(PK1, WP, 512, fb2, pos_enc, D, S,
                                              Hbuf, D, nullptr, nullptr, 0);

  // ---- layers -------------------------------------------------------------
  for (int l = 0; l < L; ++l) {
    pack_a_k<<<BS, blk, 0, stream>>>(Hbuf, HPACK);
    pack_convw_k<<<12 * 512 * 512 / 256, blk, 0, stream>>>(
        conv_w + (size_t)l * 4 * D * D * 3, WP);
    colmean_part_k<<<dim3(B, 8), blk, 0, stream>>>(Hbuf, PARTb);
    alpha_k<<<B, dim3(64), 0, stream>>>(PARTb, wm_w + (size_t)l * D * 4,
                                        wm_b + l * 4, ALPHAB);
    conv_gemm_k<<<dim3(4, BS / 128, 4), blk, 0, stream>>>(
        HPACK, WP, (const short*)ZPADF, Ybuf);
    mix_k<<<(BS * D / 4) / 256, blk, 0, stream>>>(
        Ybuf, Hbuf, conv_b + (size_t)l * 4 * D, ALPHAB, TBuf);
    layernorm_k<<<BS / 4, blk, 0, stream>>>(TBuf, g1 + l * D, be1 + l * D,
                                            TBuf, nullptr);
    // SSM skipped: scalar-per-row y cancels in LN2 (shift invariance).
    layernorm_k<<<BS / 4, blk, 0, stream>>>(TBuf, g2 + l * D, be2 + l * D,
                                            TBuf, APD);
    pack_w_k<<<512 * 2048 / 256, blk, 0, stream>>>(ffw1 + (size_t)l * D * FF,
                                                   WP, 512, 2048, 11);
    gemm_sp3<true, 1><<<gN16, blk, 0, stream>>>(APD, WP, 512,
                                                ffb1 + (size_t)l * FF, nullptr,
                                                0, 0, nullptr, 0, APFF,
                                                APFF + 2048, 4096);
    pack_w_k<<<2048 * 512 / 256, blk, 0, stream>>>(ffw2 + (size_t)l * FF * D,
                                                   WP, 2048, 512, 9);
    gemm_sp3<false, 0><<<gN4, blk, 0, stream>>>(APFF, WP, 2048,
                                                ffb2 + (size_t)l * D, TBuf, D,
                                                0, Hbuf, D, nullptr, nullptr,
                                                0);
  }

  // ---- head ---------------------------------------------------------------
  colmean_part_k<<<dim3(B, 8), blk, 0, stream>>>(Hbuf, PARTb);
  head_k<<<B, blk, 0, stream>>>(PARTb, pw1, pb1, pw2, pb2, out);
}